// Round 2
// baseline (710.833 us; speedup 1.0000x reference)
//
#include <hip/hip_runtime.h>

#define N_ATOMS   100000
#define N_BONDS   200000
#define MAX_NB    6
#define AF        39
#define BFEAT     50      // 39 + 11
#define H         128
#define DEPTH     6
#define KS_I      2       // k-steps (32 each): binput GEMM (K=64 padded)
#define KS_IH     6       // fused [fbonds(64 pad) | nei(128)] GEMM (K=192)
#define KS_O      6       // output GEMM (K=192 padded)
#define FBW       64      // padded bf16 fbonds row width
#define FAW       64      // padded bf16 fatoms row width

typedef unsigned short ushort_t;
typedef unsigned int   uint_t;

typedef __attribute__((ext_vector_type(8))) short  bf16x8;
typedef __attribute__((ext_vector_type(4))) float  f32x4;

// hardware packed f32->bf16 (RNE)
__device__ inline uint_t cvt_pk(float lo, float hi) {
    uint_t r;
    asm("v_cvt_pk_bf16_f32 %0, %1, %2" : "=v"(r) : "v"(lo), "v"(hi));
    return r;
}
__device__ inline ushort_t f2bf(float f) { return (ushort_t)cvt_pk(f, f); }

// unpack-accumulate 8 bf16 (no relu: messages are stored POST-relu)
__device__ inline void addv(float* a, uint4 v) {
    union { uint_t u; float f; } c;
    c.u = v.x << 16;          a[0] += c.f;
    c.u = v.x & 0xffff0000u;  a[1] += c.f;
    c.u = v.y << 16;          a[2] += c.f;
    c.u = v.y & 0xffff0000u;  a[3] += c.f;
    c.u = v.z << 16;          a[4] += c.f;
    c.u = v.z & 0xffff0000u;  a[5] += c.f;
    c.u = v.w << 16;          a[6] += c.f;
    c.u = v.w & 0xffff0000u;  a[7] += c.f;
}

// ---------------------------------------------------------------------------
// Pack weights to MFMA B-fragment-major bf16: p[ks][nt][lane][j],
//   n = nt*16 + (lane&15),  k = ks*32 + (lane>>4)*8 + j
// pWi : K=64  (cols 0..49 = W_i, rest 0)
// pWih: K=192 (cols 0..49 = W_i, 50..63 = 0, 64..191 = W_h)  <- fused residual
// pWo : K=192 (cols 0..127 = W_o[a_nei part], 128..166 = W_o[fatoms part])
// ---------------------------------------------------------------------------
__global__ __launch_bounds__(256) void k_pack(const float* __restrict__ W_i,
                                              const float* __restrict__ W_h,
                                              const float* __restrict__ W_o,
                                              ushort_t* __restrict__ pWi,
                                              ushort_t* __restrict__ pWih,
                                              ushort_t* __restrict__ pWo) {
    int id = blockIdx.x * 256 + threadIdx.x;   // 7168 ids
    int mat;
    ushort_t* dst;
    if (id < 1024)      { mat = 0; dst = pWi; }
    else if (id < 4096) { mat = 1; dst = pWih; id -= 1024; }
    else                { mat = 2; dst = pWo;  id -= 4096; }
    const int lane = id & 63;
    const int nt   = (id >> 6) & 7;
    const int ks   = id >> 9;
    const int n  = nt * 16 + (lane & 15);
    const int k0 = ks * 32 + (lane >> 4) * 8;
    float v[8];
#pragma unroll
    for (int j = 0; j < 8; ++j) {
        const int k = k0 + j;
        float x = 0.f;
        if (mat == 0) {
            if (k < BFEAT) x = W_i[n * BFEAT + k];
        } else if (mat == 1) {
            if (k < BFEAT)     x = W_i[n * BFEAT + k];
            else if (k >= FBW) x = W_h[n * H + (k - FBW)];
        } else {
            if (k < H)           x = W_o[(size_t)n * (AF + H) + AF + k];
            else if (k < H + AF) x = W_o[(size_t)n * (AF + H) + (k - H)];
        }
        v[j] = x;
    }
    uint4 u;
    u.x = cvt_pk(v[0], v[1]); u.y = cvt_pk(v[2], v[3]);
    u.z = cvt_pk(v[4], v[5]); u.w = cvt_pk(v[6], v[7]);
    ((uint4*)dst)[id] = u;
}

// ---------------------------------------------------------------------------
// Pad fatoms to bf16[N_ATOMS][64] in MFMA-fragment-readable layout.
// ---------------------------------------------------------------------------
__global__ __launch_bounds__(256) void k_fab(const float* __restrict__ fatoms,
                                             ushort_t* __restrict__ fab) {
    const int t = threadIdx.x;
    const int a0 = blockIdx.x * 64;
    const int row = t >> 2;
    const int c0 = (t & 3) * 16;
    const int a = a0 + row;
    if (a >= N_ATOMS) return;
    float v[16];
#pragma unroll
    for (int j = 0; j < 16; ++j) {
        const int c = c0 + j;
        v[j] = (c < AF) ? fatoms[(size_t)a * AF + c] : 0.f;
    }
    uint4 u0, u1;
    u0.x = cvt_pk(v[0],  v[1]);  u0.y = cvt_pk(v[2],  v[3]);
    u0.z = cvt_pk(v[4],  v[5]);  u0.w = cvt_pk(v[6],  v[7]);
    u1.x = cvt_pk(v[8],  v[9]);  u1.y = cvt_pk(v[10], v[11]);
    u1.z = cvt_pk(v[12], v[13]); u1.w = cvt_pk(v[14], v[15]);
    *(uint4*)(fab + (size_t)a * FAW + c0)     = u0;
    *(uint4*)(fab + (size_t)a * FAW + c0 + 8) = u1;
}

// ---------------------------------------------------------------------------
// msg0 = relu(fbonds @ W_i^T) in bf16 (POST-relu), and dump padded bf16
// fbonds rows (width 64) for the fused k_mp steps.
// ---------------------------------------------------------------------------
__global__ __launch_bounds__(256) void k_binput(const float* __restrict__ fbonds,
                                                const ushort_t* __restrict__ pWi,
                                                ushort_t* __restrict__ fbb,
                                                ushort_t* __restrict__ msg0) {
    __shared__ __align__(16) ushort_t sAC[64][136];
    const int t = threadIdx.x;
    const int b0 = blockIdx.x * 64;

    for (int i = t; i < 64 * 25; i += 256) {
        const int row = i / 25, j = i % 25;
        const float2 v = *(const float2*)(fbonds + (size_t)(b0 + row) * BFEAT + j * 2);
        *(uint_t*)&sAC[row][j * 2] = cvt_pk(v.x, v.y);
    }
    for (int i = t; i < 64 * 7; i += 256) {
        const int row = i / 7, c = BFEAT + (i % 7) * 2;
        *(uint_t*)&sAC[row][c] = 0u;
    }
    __syncthreads();

    // persist bf16 fbonds (64 cols incl. zero pad) -> fbb
    for (int i = t; i < 64 * 8; i += 256) {
        const int row = i >> 3, c0 = (i & 7) * 8;
        *(uint4*)(fbb + (size_t)(b0 + row) * FBW + c0) = *(const uint4*)&sAC[row][c0];
    }

    const int w    = t >> 6;
    const int lane = t & 63;
    const int col  = lane & 15;
    const int kg   = lane >> 4;
    const int m    = 16 * w + col;

    f32x4 acc[8];
#pragma unroll
    for (int nt = 0; nt < 8; ++nt) acc[nt] = (f32x4){0.f, 0.f, 0.f, 0.f};
    bf16x8 af[KS_I];
#pragma unroll
    for (int ks = 0; ks < KS_I; ++ks)
        af[ks] = *(const bf16x8*)&sAC[m][ks * 32 + kg * 8];
#pragma unroll
    for (int ks = 0; ks < KS_I; ++ks) {
#pragma unroll
        for (int nt = 0; nt < 8; ++nt) {
            const bf16x8 b = *(const bf16x8*)(pWi + (((size_t)(ks * 8 + nt) * 64 + lane) * 8));
            acc[nt] = __builtin_amdgcn_mfma_f32_16x16x32_bf16(af[ks], b, acc[nt], 0, 0, 0);
        }
    }
    __syncthreads();   // fbb-copy reads done before C overwrite

    const int row0 = kg * 4;
#pragma unroll
    for (int nt = 0; nt < 8; ++nt)
#pragma unroll
        for (int r = 0; r < 4; ++r)
            sAC[16 * w + row0 + r][nt * 16 + col] = f2bf(fmaxf(acc[nt][r], 0.f));
    __syncthreads();

    for (int i = t; i < 64 * 16; i += 256) {
        const int row = i >> 4, c0 = (i & 15) * 8;
        *(uint4*)(msg0 + (size_t)(b0 + row) * H + c0) = *(const uint4*)&sAC[row][c0];
    }
}

// ---------------------------------------------------------------------------
// Fused MP step: msg_out = relu([fbonds_bf16 | gather-sum(msg_in)] @ [W_i|W_h]^T)
// fbonds A-frags loaded per-lane direct from fbb (16B each) -> no LDS staging.
// LDS: sAC[64][136] (nei + C) 17408 + sIdx 1536 = 18944 -> 8 blocks/CU.
// ---------------------------------------------------------------------------
__global__ __launch_bounds__(256, 8) void k_mp(const ushort_t* __restrict__ msg_in,
                                               const int* __restrict__ bgraph,
                                               const ushort_t* __restrict__ pWih,
                                               const ushort_t* __restrict__ fbb,
                                               ushort_t* __restrict__ msg_out) {
    __shared__ __align__(16) ushort_t sAC[64][136];   // nei cols 0..127; C overwrites
    __shared__ int sIdx[64][MAX_NB];
    const int t = threadIdx.x;
    const int b0 = blockIdx.x * 64;

    for (int i = t; i < 64 * MAX_NB; i += 256)
        sIdx[i / MAX_NB][i % MAX_NB] = bgraph[(size_t)b0 * MAX_NB + i];
    __syncthreads();

    {   // gather-sum (no relu) -> bf16 A tile cols 0..127, merged 2-passes
        const int bi = t >> 4;
        const int c0 = (t & 15) * 8;
#pragma unroll
        for (int p = 0; p < 4; p += 2) {
            const int iA = p * 16 + bi;
            const int iB = iA + 16;
            uint4 vA[MAX_NB], vB[MAX_NB];
#pragma unroll
            for (int j = 0; j < MAX_NB; ++j)
                vA[j] = *(const uint4*)(msg_in + (size_t)sIdx[iA][j] * H + c0);
#pragma unroll
            for (int j = 0; j < MAX_NB; ++j)
                vB[j] = *(const uint4*)(msg_in + (size_t)sIdx[iB][j] * H + c0);
            float a[8], b[8];
#pragma unroll
            for (int q = 0; q < 8; ++q) { a[q] = 0.f; b[q] = 0.f; }
#pragma unroll
            for (int j = 0; j < MAX_NB; ++j) addv(a, vA[j]);
#pragma unroll
            for (int j = 0; j < MAX_NB; ++j) addv(b, vB[j]);
            uint4 ua, ub;
            ua.x = cvt_pk(a[0], a[1]); ua.y = cvt_pk(a[2], a[3]);
            ua.z = cvt_pk(a[4], a[5]); ua.w = cvt_pk(a[6], a[7]);
            ub.x = cvt_pk(b[0], b[1]); ub.y = cvt_pk(b[2], b[3]);
            ub.z = cvt_pk(b[4], b[5]); ub.w = cvt_pk(b[6], b[7]);
            *(uint4*)&sAC[iA][c0] = ua;
            *(uint4*)&sAC[iB][c0] = ub;
        }
    }

    const int w    = t >> 6;
    const int lane = t & 63;
    const int col  = lane & 15;
    const int kg   = lane >> 4;
    const int m    = 16 * w + col;

    bf16x8 af[KS_IH];
    // fbonds frags direct from global (latency hides under barrier wait)
    af[0] = *(const bf16x8*)(fbb + (size_t)(b0 + m) * FBW + kg * 8);
    af[1] = *(const bf16x8*)(fbb + (size_t)(b0 + m) * FBW + 32 + kg * 8);
    __syncthreads();
#pragma unroll
    for (int ks = 2; ks < KS_IH; ++ks)
        af[ks] = *(const bf16x8*)&sAC[m][(ks - 2) * 32 + kg * 8];

    f32x4 acc[8];
#pragma unroll
    for (int nt = 0; nt < 8; ++nt) acc[nt] = (f32x4){0.f, 0.f, 0.f, 0.f};
#pragma unroll
    for (int ks = 0; ks < KS_IH; ++ks) {
#pragma unroll
        for (int nt = 0; nt < 8; ++nt) {
            const bf16x8 b = *(const bf16x8*)(pWih + (((size_t)(ks * 8 + nt) * 64 + lane) * 8));
            acc[nt] = __builtin_amdgcn_mfma_f32_16x16x32_bf16(af[ks], b, acc[nt], 0, 0, 0);
        }
    }
    // relu + bf16 C into own rows (per-wave slab; af pre-loaded, no barrier)
    const int row0 = kg * 4;
#pragma unroll
    for (int nt = 0; nt < 8; ++nt)
#pragma unroll
        for (int r = 0; r < 4; ++r)
            sAC[16 * w + row0 + r][nt * 16 + col] = f2bf(fmaxf(acc[nt][r], 0.f));
    __syncthreads();

    for (int i = t; i < 64 * 16; i += 256) {
        const int row = i >> 4, c0 = (i & 15) * 8;
        *(uint4*)(msg_out + (size_t)(b0 + row) * H + c0) = *(const uint4*)&sAC[row][c0];
    }
}

// ---------------------------------------------------------------------------
// Fused output: out = relu(b_o + [gather(128) | fatoms_bf16(64)] @ W_o^T)
// fatoms frags per-lane from fab; C stored DIRECT to global (no sC, no union).
// LDS: sA[64][136] 17408 + sIdx 1536 = 18944 -> 8 blocks/CU.
// ---------------------------------------------------------------------------
__global__ __launch_bounds__(256, 8) void k_out(const ushort_t* __restrict__ msg,
                                                const int* __restrict__ agraph,
                                                const ushort_t* __restrict__ fab,
                                                const ushort_t* __restrict__ pWo,
                                                const float* __restrict__ b_o,
                                                float* __restrict__ out) {
    __shared__ __align__(16) ushort_t sA[64][136];
    __shared__ int sIdx[64][MAX_NB];
    const int t = threadIdx.x;
    const int a0 = blockIdx.x * 64;

    for (int i = t; i < 64 * MAX_NB; i += 256) {
        const int a = a0 + i / MAX_NB;
        sIdx[i / MAX_NB][i % MAX_NB] = (a < N_ATOMS) ? agraph[(size_t)a * MAX_NB + (i % MAX_NB)] : 0;
    }
    __syncthreads();

    {   // a_nei gather-sum -> cols 0..127, merged 2-passes
        const int bi = t >> 4;
        const int c0 = (t & 15) * 8;
#pragma unroll
        for (int p = 0; p < 4; p += 2) {
            const int iA = p * 16 + bi;
            const int iB = iA + 16;
            uint4 vA[MAX_NB], vB[MAX_NB];
#pragma unroll
            for (int j = 0; j < MAX_NB; ++j)
                vA[j] = *(const uint4*)(msg + (size_t)sIdx[iA][j] * H + c0);
#pragma unroll
            for (int j = 0; j < MAX_NB; ++j)
                vB[j] = *(const uint4*)(msg + (size_t)sIdx[iB][j] * H + c0);
            float a[8], b[8];
#pragma unroll
            for (int q = 0; q < 8; ++q) { a[q] = 0.f; b[q] = 0.f; }
#pragma unroll
            for (int j = 0; j < MAX_NB; ++j) addv(a, vA[j]);
#pragma unroll
            for (int j = 0; j < MAX_NB; ++j) addv(b, vB[j]);
            uint4 ua, ub;
            ua.x = cvt_pk(a[0], a[1]); ua.y = cvt_pk(a[2], a[3]);
            ua.z = cvt_pk(a[4], a[5]); ua.w = cvt_pk(a[6], a[7]);
            ub.x = cvt_pk(b[0], b[1]); ub.y = cvt_pk(b[2], b[3]);
            ub.z = cvt_pk(b[4], b[5]); ub.w = cvt_pk(b[6], b[7]);
            *(uint4*)&sA[iA][c0] = ua;
            *(uint4*)&sA[iB][c0] = ub;
        }
    }

    const int w    = t >> 6;
    const int lane = t & 63;
    const int col  = lane & 15;
    const int kg   = lane >> 4;
    const int m    = 16 * w + col;
    const int am   = a0 + m;
    const size_t amc = (size_t)((am < N_ATOMS) ? am : 0);   // clamp (unused rows)

    bf16x8 af[KS_O];
    af[4] = *(const bf16x8*)(fab + amc * FAW + kg * 8);
    af[5] = *(const bf16x8*)(fab + amc * FAW + 32 + kg * 8);
    __syncthreads();
#pragma unroll
    for (int ks = 0; ks < 4; ++ks)
        af[ks] = *(const bf16x8*)&sA[m][ks * 32 + kg * 8];

    f32x4 acc[8];
#pragma unroll
    for (int nt = 0; nt < 8; ++nt) acc[nt] = (f32x4){0.f, 0.f, 0.f, 0.f};
#pragma unroll
    for (int ks = 0; ks < KS_O; ++ks) {
#pragma unroll
        for (int nt = 0; nt < 8; ++nt) {
            const bf16x8 b = *(const bf16x8*)(pWo + (((size_t)(ks * 8 + nt) * 64 + lane) * 8));
            acc[nt] = __builtin_amdgcn_mfma_f32_16x16x32_bf16(af[ks], b, acc[nt], 0, 0, 0);
        }
    }

    // direct epilogue: bias + relu + scattered f32 stores (4x64B segments/wave-store)
    float bias[8];
#pragma unroll
    for (int nt = 0; nt < 8; ++nt) bias[nt] = b_o[nt * 16 + col];
    const int rowbase = a0 + 16 * w + kg * 4;
#pragma unroll
    for (int nt = 0; nt < 8; ++nt) {
#pragma unroll
        for (int r = 0; r < 4; ++r) {
            const int arow = rowbase + r;
            if (arow < N_ATOMS)
                out[(size_t)arow * H + nt * 16 + col] = fmaxf(acc[nt][r] + bias[nt], 0.f);
        }
    }
}

// ---------------------------------------------------------------------------
extern "C" void kernel_launch(void* const* d_in, const int* in_sizes, int n_in,
                              void* d_out, int out_size, void* d_ws, size_t ws_size,
                              hipStream_t stream) {
    const float* fatoms = (const float*)d_in[0];
    const float* fbonds = (const float*)d_in[1];
    const int*   agraph = (const int*)d_in[2];
    const int*   bgraph = (const int*)d_in[3];
    const float* W_i    = (const float*)d_in[4];
    const float* W_h    = (const float*)d_in[5];
    const float* W_o    = (const float*)d_in[6];
    const float* b_o    = (const float*)d_in[7];
    float* out = (float*)d_out;

    const size_t MSG_BYTES = (size_t)N_BONDS * H * sizeof(ushort_t);     // 51.2 MB
    const size_t FBB_BYTES = (size_t)N_BONDS * FBW * sizeof(ushort_t);   // 25.6 MB
    const size_t FAB_BYTES = (size_t)N_ATOMS * FAW * sizeof(ushort_t);   // 12.8 MB
    char* ws = (char*)d_ws;
    ushort_t* m0   = (ushort_t*)(ws);
    ushort_t* m1   = (ushort_t*)(ws + MSG_BYTES);
    ushort_t* fbb  = (ushort_t*)(ws + 2 * MSG_BYTES);
    ushort_t* fab  = (ushort_t*)(ws + 2 * MSG_BYTES + FBB_BYTES);
    char*     wb   = ws + 2 * MSG_BYTES + FBB_BYTES + FAB_BYTES;
    ushort_t* pWi  = (ushort_t*)(wb);              // 16 KB
    ushort_t* pWih = (ushort_t*)(wb + 16 * 1024);  // 48 KB
    ushort_t* pWo  = (ushort_t*)(wb + 64 * 1024);  // 48 KB

    k_pack<<<28, 256, 0, stream>>>(W_i, W_h, W_o, pWi, pWih, pWo);
    k_fab<<<(N_ATOMS + 63) / 64, 256, 0, stream>>>(fatoms, fab);
    k_binput<<<N_BONDS / 64, 256, 0, stream>>>(fbonds, pWi, fbb, m0);

    ushort_t* cur = m0;
    ushort_t* nxt = m1;
    for (int d = 0; d < DEPTH - 1; ++d) {
        k_mp<<<N_BONDS / 64, 256, 0, stream>>>(cur, bgraph, pWih, fbb, nxt);
        ushort_t* tmp = cur; cur = nxt; nxt = tmp;
    }

    k_out<<<(N_ATOMS + 63) / 64, 256, 0, stream>>>(cur, agraph, fab, pWo, b_o, out);
}

// Round 3
// 466.967 us; speedup vs baseline: 1.5222x; 1.5222x over previous
//
#include <hip/hip_runtime.h>

#define N_ATOMS   100000
#define N_BONDS   200000
#define MAX_NB    6
#define AF        39
#define BFEAT     50      // 39 + 11
#define H         128
#define DEPTH     6
#define KS_I      2       // k-steps (32 each): binput GEMM (K=64 padded)
#define KS_IH     6       // fused [fbonds(64 pad) | nei(128)] GEMM (K=192)
#define KS_O      6       // output GEMM (K=192 padded)
#define FBW       64      // padded bf16 fbonds row width
#define FAW       64      // padded bf16 fatoms row width

typedef unsigned short ushort_t;
typedef unsigned int   uint_t;

typedef __attribute__((ext_vector_type(8))) short  bf16x8;
typedef __attribute__((ext_vector_type(4))) float  f32x4;

// hardware packed f32->bf16 (RNE)
__device__ inline uint_t cvt_pk(float lo, float hi) {
    uint_t r;
    asm("v_cvt_pk_bf16_f32 %0, %1, %2" : "=v"(r) : "v"(lo), "v"(hi));
    return r;
}
__device__ inline ushort_t f2bf(float f) { return (ushort_t)cvt_pk(f, f); }

// unpack-accumulate 8 bf16 (no relu: messages are stored POST-relu)
__device__ inline void addv(float* a, uint4 v) {
    union { uint_t u; float f; } c;
    c.u = v.x << 16;          a[0] += c.f;
    c.u = v.x & 0xffff0000u;  a[1] += c.f;
    c.u = v.y << 16;          a[2] += c.f;
    c.u = v.y & 0xffff0000u;  a[3] += c.f;
    c.u = v.z << 16;          a[4] += c.f;
    c.u = v.z & 0xffff0000u;  a[5] += c.f;
    c.u = v.w << 16;          a[6] += c.f;
    c.u = v.w & 0xffff0000u;  a[7] += c.f;
}

// ---------------------------------------------------------------------------
// Pack weights to MFMA B-fragment-major bf16: p[ks][nt][lane][j],
//   n = nt*16 + (lane&15),  k = ks*32 + (lane>>4)*8 + j
// pWi : K=64  (cols 0..49 = W_i, rest 0)
// pWih: K=192 (cols 0..49 = W_i, 50..63 = 0, 64..191 = W_h)  <- fused residual
// pWo : K=192 (cols 0..127 = W_o[a_nei part], 128..166 = W_o[fatoms part])
// ---------------------------------------------------------------------------
__global__ __launch_bounds__(256) void k_pack(const float* __restrict__ W_i,
                                              const float* __restrict__ W_h,
                                              const float* __restrict__ W_o,
                                              ushort_t* __restrict__ pWi,
                                              ushort_t* __restrict__ pWih,
                                              ushort_t* __restrict__ pWo) {
    int id = blockIdx.x * 256 + threadIdx.x;   // 7168 ids
    int mat;
    ushort_t* dst;
    if (id < 1024)      { mat = 0; dst = pWi; }
    else if (id < 4096) { mat = 1; dst = pWih; id -= 1024; }
    else                { mat = 2; dst = pWo;  id -= 4096; }
    const int lane = id & 63;
    const int nt   = (id >> 6) & 7;
    const int ks   = id >> 9;
    const int n  = nt * 16 + (lane & 15);
    const int k0 = ks * 32 + (lane >> 4) * 8;
    float v[8];
#pragma unroll
    for (int j = 0; j < 8; ++j) {
        const int k = k0 + j;
        float x = 0.f;
        if (mat == 0) {
            if (k < BFEAT) x = W_i[n * BFEAT + k];
        } else if (mat == 1) {
            if (k < BFEAT)     x = W_i[n * BFEAT + k];
            else if (k >= FBW) x = W_h[n * H + (k - FBW)];
        } else {
            if (k < H)           x = W_o[(size_t)n * (AF + H) + AF + k];
            else if (k < H + AF) x = W_o[(size_t)n * (AF + H) + (k - H)];
        }
        v[j] = x;
    }
    uint4 u;
    u.x = cvt_pk(v[0], v[1]); u.y = cvt_pk(v[2], v[3]);
    u.z = cvt_pk(v[4], v[5]); u.w = cvt_pk(v[6], v[7]);
    ((uint4*)dst)[id] = u;
}

// ---------------------------------------------------------------------------
// Pad fatoms to bf16[N_ATOMS][64] in MFMA-fragment-readable layout.
// ---------------------------------------------------------------------------
__global__ __launch_bounds__(256) void k_fab(const float* __restrict__ fatoms,
                                             ushort_t* __restrict__ fab) {
    const int t = threadIdx.x;
    const int a0 = blockIdx.x * 64;
    const int row = t >> 2;
    const int c0 = (t & 3) * 16;
    const int a = a0 + row;
    if (a >= N_ATOMS) return;
    float v[16];
#pragma unroll
    for (int j = 0; j < 16; ++j) {
        const int c = c0 + j;
        v[j] = (c < AF) ? fatoms[(size_t)a * AF + c] : 0.f;
    }
    uint4 u0, u1;
    u0.x = cvt_pk(v[0],  v[1]);  u0.y = cvt_pk(v[2],  v[3]);
    u0.z = cvt_pk(v[4],  v[5]);  u0.w = cvt_pk(v[6],  v[7]);
    u1.x = cvt_pk(v[8],  v[9]);  u1.y = cvt_pk(v[10], v[11]);
    u1.z = cvt_pk(v[12], v[13]); u1.w = cvt_pk(v[14], v[15]);
    *(uint4*)(fab + (size_t)a * FAW + c0)     = u0;
    *(uint4*)(fab + (size_t)a * FAW + c0 + 8) = u1;
}

// ---------------------------------------------------------------------------
// msg0 = relu(fbonds @ W_i^T) in bf16 (POST-relu), and dump padded bf16
// fbonds rows (width 64) for the fused k_mp steps.
// ---------------------------------------------------------------------------
__global__ __launch_bounds__(256) void k_binput(const float* __restrict__ fbonds,
                                                const ushort_t* __restrict__ pWi,
                                                ushort_t* __restrict__ fbb,
                                                ushort_t* __restrict__ msg0) {
    __shared__ __align__(16) ushort_t sAC[64][136];
    const int t = threadIdx.x;
    const int b0 = blockIdx.x * 64;

    for (int i = t; i < 64 * 25; i += 256) {
        const int row = i / 25, j = i % 25;
        const float2 v = *(const float2*)(fbonds + (size_t)(b0 + row) * BFEAT + j * 2);
        *(uint_t*)&sAC[row][j * 2] = cvt_pk(v.x, v.y);
    }
    for (int i = t; i < 64 * 7; i += 256) {
        const int row = i / 7, c = BFEAT + (i % 7) * 2;
        *(uint_t*)&sAC[row][c] = 0u;
    }
    __syncthreads();

    // persist bf16 fbonds (64 cols incl. zero pad) -> fbb
    for (int i = t; i < 64 * 8; i += 256) {
        const int row = i >> 3, c0 = (i & 7) * 8;
        *(uint4*)(fbb + (size_t)(b0 + row) * FBW + c0) = *(const uint4*)&sAC[row][c0];
    }

    const int w    = t >> 6;
    const int lane = t & 63;
    const int col  = lane & 15;
    const int kg   = lane >> 4;
    const int m    = 16 * w + col;

    f32x4 acc[8];
#pragma unroll
    for (int nt = 0; nt < 8; ++nt) acc[nt] = (f32x4){0.f, 0.f, 0.f, 0.f};
    bf16x8 af[KS_I];
#pragma unroll
    for (int ks = 0; ks < KS_I; ++ks)
        af[ks] = *(const bf16x8*)&sAC[m][ks * 32 + kg * 8];
#pragma unroll
    for (int ks = 0; ks < KS_I; ++ks) {
#pragma unroll
        for (int nt = 0; nt < 8; ++nt) {
            const bf16x8 b = *(const bf16x8*)(pWi + (((size_t)(ks * 8 + nt) * 64 + lane) * 8));
            acc[nt] = __builtin_amdgcn_mfma_f32_16x16x32_bf16(af[ks], b, acc[nt], 0, 0, 0);
        }
    }
    __syncthreads();   // fbb-copy reads done before C overwrite

    const int row0 = kg * 4;
#pragma unroll
    for (int nt = 0; nt < 8; ++nt)
#pragma unroll
        for (int r = 0; r < 4; ++r)
            sAC[16 * w + row0 + r][nt * 16 + col] = f2bf(fmaxf(acc[nt][r], 0.f));
    __syncthreads();

    for (int i = t; i < 64 * 16; i += 256) {
        const int row = i >> 4, c0 = (i & 15) * 8;
        *(uint4*)(msg0 + (size_t)(b0 + row) * H + c0) = *(const uint4*)&sAC[row][c0];
    }
}

// ---------------------------------------------------------------------------
// Fused MP step: msg_out = relu([fbonds_bf16 | gather-sum(msg_in)] @ [W_i|W_h]^T)
// fbonds A-frags loaded per-lane direct from fbb (16B each) -> no LDS staging.
// LDS: sAC[64][136] (nei + C) 17408 + sIdx 1536 = 18944.
// NOTE: plain launch_bounds — (256,8) in R2 forced VGPR=32 -> spills
// (WRITE_SIZE 50->159 MB). VGPR budget is the binding constraint here.
// ---------------------------------------------------------------------------
__global__ __launch_bounds__(256) void k_mp(const ushort_t* __restrict__ msg_in,
                                            const int* __restrict__ bgraph,
                                            const ushort_t* __restrict__ pWih,
                                            const ushort_t* __restrict__ fbb,
                                            ushort_t* __restrict__ msg_out) {
    __shared__ __align__(16) ushort_t sAC[64][136];   // nei cols 0..127; C overwrites
    __shared__ int sIdx[64][MAX_NB];
    const int t = threadIdx.x;
    const int b0 = blockIdx.x * 64;

    for (int i = t; i < 64 * MAX_NB; i += 256)
        sIdx[i / MAX_NB][i % MAX_NB] = bgraph[(size_t)b0 * MAX_NB + i];
    __syncthreads();

    {   // gather-sum (no relu) -> bf16 A tile cols 0..127, merged 2-passes
        const int bi = t >> 4;
        const int c0 = (t & 15) * 8;
#pragma unroll
        for (int p = 0; p < 4; p += 2) {
            const int iA = p * 16 + bi;
            const int iB = iA + 16;
            uint4 vA[MAX_NB], vB[MAX_NB];
#pragma unroll
            for (int j = 0; j < MAX_NB; ++j)
                vA[j] = *(const uint4*)(msg_in + (size_t)sIdx[iA][j] * H + c0);
#pragma unroll
            for (int j = 0; j < MAX_NB; ++j)
                vB[j] = *(const uint4*)(msg_in + (size_t)sIdx[iB][j] * H + c0);
            float a[8], b[8];
#pragma unroll
            for (int q = 0; q < 8; ++q) { a[q] = 0.f; b[q] = 0.f; }
#pragma unroll
            for (int j = 0; j < MAX_NB; ++j) addv(a, vA[j]);
#pragma unroll
            for (int j = 0; j < MAX_NB; ++j) addv(b, vB[j]);
            uint4 ua, ub;
            ua.x = cvt_pk(a[0], a[1]); ua.y = cvt_pk(a[2], a[3]);
            ua.z = cvt_pk(a[4], a[5]); ua.w = cvt_pk(a[6], a[7]);
            ub.x = cvt_pk(b[0], b[1]); ub.y = cvt_pk(b[2], b[3]);
            ub.z = cvt_pk(b[4], b[5]); ub.w = cvt_pk(b[6], b[7]);
            *(uint4*)&sAC[iA][c0] = ua;
            *(uint4*)&sAC[iB][c0] = ub;
        }
    }

    const int w    = t >> 6;
    const int lane = t & 63;
    const int col  = lane & 15;
    const int kg   = lane >> 4;
    const int m    = 16 * w + col;

    bf16x8 af[KS_IH];
    // fbonds frags direct from global (latency hides under barrier wait)
    af[0] = *(const bf16x8*)(fbb + (size_t)(b0 + m) * FBW + kg * 8);
    af[1] = *(const bf16x8*)(fbb + (size_t)(b0 + m) * FBW + 32 + kg * 8);
    __syncthreads();
#pragma unroll
    for (int ks = 2; ks < KS_IH; ++ks)
        af[ks] = *(const bf16x8*)&sAC[m][(ks - 2) * 32 + kg * 8];

    f32x4 acc[8];
#pragma unroll
    for (int nt = 0; nt < 8; ++nt) acc[nt] = (f32x4){0.f, 0.f, 0.f, 0.f};
#pragma unroll
    for (int ks = 0; ks < KS_IH; ++ks) {
#pragma unroll
        for (int nt = 0; nt < 8; ++nt) {
            const bf16x8 b = *(const bf16x8*)(pWih + (((size_t)(ks * 8 + nt) * 64 + lane) * 8));
            acc[nt] = __builtin_amdgcn_mfma_f32_16x16x32_bf16(af[ks], b, acc[nt], 0, 0, 0);
        }
    }
    // relu + bf16 C into own rows (per-wave slab; af pre-loaded, no barrier)
    const int row0 = kg * 4;
#pragma unroll
    for (int nt = 0; nt < 8; ++nt)
#pragma unroll
        for (int r = 0; r < 4; ++r)
            sAC[16 * w + row0 + r][nt * 16 + col] = f2bf(fmaxf(acc[nt][r], 0.f));
    __syncthreads();

    for (int i = t; i < 64 * 16; i += 256) {
        const int row = i >> 4, c0 = (i & 15) * 8;
        *(uint4*)(msg_out + (size_t)(b0 + row) * H + c0) = *(const uint4*)&sAC[row][c0];
    }
}

// ---------------------------------------------------------------------------
// Fused output: out = relu(b_o + [gather(128) | fatoms_bf16(64)] @ W_o^T)
// fatoms frags per-lane from fab; C stored DIRECT to global (no sC, no union).
// LDS: sA[64][136] 17408 + sIdx 1536 = 18944. Plain launch_bounds (see k_mp).
// ---------------------------------------------------------------------------
__global__ __launch_bounds__(256) void k_out(const ushort_t* __restrict__ msg,
                                             const int* __restrict__ agraph,
                                             const ushort_t* __restrict__ fab,
                                             const ushort_t* __restrict__ pWo,
                                             const float* __restrict__ b_o,
                                             float* __restrict__ out) {
    __shared__ __align__(16) ushort_t sA[64][136];
    __shared__ int sIdx[64][MAX_NB];
    const int t = threadIdx.x;
    const int a0 = blockIdx.x * 64;

    for (int i = t; i < 64 * MAX_NB; i += 256) {
        const int a = a0 + i / MAX_NB;
        sIdx[i / MAX_NB][i % MAX_NB] = (a < N_ATOMS) ? agraph[(size_t)a * MAX_NB + (i % MAX_NB)] : 0;
    }
    __syncthreads();

    {   // a_nei gather-sum -> cols 0..127, merged 2-passes
        const int bi = t >> 4;
        const int c0 = (t & 15) * 8;
#pragma unroll
        for (int p = 0; p < 4; p += 2) {
            const int iA = p * 16 + bi;
            const int iB = iA + 16;
            uint4 vA[MAX_NB], vB[MAX_NB];
#pragma unroll
            for (int j = 0; j < MAX_NB; ++j)
                vA[j] = *(const uint4*)(msg + (size_t)sIdx[iA][j] * H + c0);
#pragma unroll
            for (int j = 0; j < MAX_NB; ++j)
                vB[j] = *(const uint4*)(msg + (size_t)sIdx[iB][j] * H + c0);
            float a[8], b[8];
#pragma unroll
            for (int q = 0; q < 8; ++q) { a[q] = 0.f; b[q] = 0.f; }
#pragma unroll
            for (int j = 0; j < MAX_NB; ++j) addv(a, vA[j]);
#pragma unroll
            for (int j = 0; j < MAX_NB; ++j) addv(b, vB[j]);
            uint4 ua, ub;
            ua.x = cvt_pk(a[0], a[1]); ua.y = cvt_pk(a[2], a[3]);
            ua.z = cvt_pk(a[4], a[5]); ua.w = cvt_pk(a[6], a[7]);
            ub.x = cvt_pk(b[0], b[1]); ub.y = cvt_pk(b[2], b[3]);
            ub.z = cvt_pk(b[4], b[5]); ub.w = cvt_pk(b[6], b[7]);
            *(uint4*)&sA[iA][c0] = ua;
            *(uint4*)&sA[iB][c0] = ub;
        }
    }

    const int w    = t >> 6;
    const int lane = t & 63;
    const int col  = lane & 15;
    const int kg   = lane >> 4;
    const int m    = 16 * w + col;
    const int am   = a0 + m;
    const size_t amc = (size_t)((am < N_ATOMS) ? am : 0);   // clamp (unused rows)

    bf16x8 af[KS_O];
    af[4] = *(const bf16x8*)(fab + amc * FAW + kg * 8);
    af[5] = *(const bf16x8*)(fab + amc * FAW + 32 + kg * 8);
    __syncthreads();
#pragma unroll
    for (int ks = 0; ks < 4; ++ks)
        af[ks] = *(const bf16x8*)&sA[m][ks * 32 + kg * 8];

    f32x4 acc[8];
#pragma unroll
    for (int nt = 0; nt < 8; ++nt) acc[nt] = (f32x4){0.f, 0.f, 0.f, 0.f};
#pragma unroll
    for (int ks = 0; ks < KS_O; ++ks) {
#pragma unroll
        for (int nt = 0; nt < 8; ++nt) {
            const bf16x8 b = *(const bf16x8*)(pWo + (((size_t)(ks * 8 + nt) * 64 + lane) * 8));
            acc[nt] = __builtin_amdgcn_mfma_f32_16x16x32_bf16(af[ks], b, acc[nt], 0, 0, 0);
        }
    }

    // direct epilogue: bias + relu + scattered f32 stores (4x64B segments/wave-store)
    float bias[8];
#pragma unroll
    for (int nt = 0; nt < 8; ++nt) bias[nt] = b_o[nt * 16 + col];
    const int rowbase = a0 + 16 * w + kg * 4;
#pragma unroll
    for (int nt = 0; nt < 8; ++nt) {
#pragma unroll
        for (int r = 0; r < 4; ++r) {
            const int arow = rowbase + r;
            if (arow < N_ATOMS)
                out[(size_t)arow * H + nt * 16 + col] = fmaxf(acc[nt][r] + bias[nt], 0.f);
        }
    }
}

// ---------------------------------------------------------------------------
extern "C" void kernel_launch(void* const* d_in, const int* in_sizes, int n_in,
                              void* d_out, int out_size, void* d_ws, size_t ws_size,
                              hipStream_t stream) {
    const float* fatoms = (const float*)d_in[0];
    const float* fbonds = (const float*)d_in[1];
    const int*   agraph = (const int*)d_in[2];
    const int*   bgraph = (const int*)d_in[3];
    const float* W_i    = (const float*)d_in[4];
    const float* W_h    = (const float*)d_in[5];
    const float* W_o    = (const float*)d_in[6];
    const float* b_o    = (const float*)d_in[7];
    float* out = (float*)d_out;

    const size_t MSG_BYTES = (size_t)N_BONDS * H * sizeof(ushort_t);     // 51.2 MB
    const size_t FBB_BYTES = (size_t)N_BONDS * FBW * sizeof(ushort_t);   // 25.6 MB
    const size_t FAB_BYTES = (size_t)N_ATOMS * FAW * sizeof(ushort_t);   // 12.8 MB
    char* ws = (char*)d_ws;
    ushort_t* m0   = (ushort_t*)(ws);
    ushort_t* m1   = (ushort_t*)(ws + MSG_BYTES);
    ushort_t* fbb  = (ushort_t*)(ws + 2 * MSG_BYTES);
    ushort_t* fab  = (ushort_t*)(ws + 2 * MSG_BYTES + FBB_BYTES);
    char*     wb   = ws + 2 * MSG_BYTES + FBB_BYTES + FAB_BYTES;
    ushort_t* pWi  = (ushort_t*)(wb);              // 16 KB
    ushort_t* pWih = (ushort_t*)(wb + 16 * 1024);  // 48 KB
    ushort_t* pWo  = (ushort_t*)(wb + 64 * 1024);  // 48 KB

    k_pack<<<28, 256, 0, stream>>>(W_i, W_h, W_o, pWi, pWih, pWo);
    k_fab<<<(N_ATOMS + 63) / 64, 256, 0, stream>>>(fatoms, fab);
    k_binput<<<N_BONDS / 64, 256, 0, stream>>>(fbonds, pWi, fbb, m0);

    ushort_t* cur = m0;
    ushort_t* nxt = m1;
    for (int d = 0; d < DEPTH - 1; ++d) {
        k_mp<<<N_BONDS / 64, 256, 0, stream>>>(cur, bgraph, pWih, fbb, nxt);
        ushort_t* tmp = cur; cur = nxt; nxt = tmp;
    }

    k_out<<<(N_ATOMS + 63) / 64, 256, 0, stream>>>(cur, agraph, fab, pWo, b_o, out);
}